// Round 10
// baseline (207.453 us; speedup 1.0000x reference)
//
#include <hip/hip_runtime.h>
#include <hip/hip_bf16.h>

#define N_NODES 100000
#define N_EDGES 1600000
#define IN_FEAT 128
#define HIDDEN 64
#define OUT_FEAT 32
#define CAP 64          // padded CSR slots/node
#define NP 100352       // padded node count
#define PS 68           // LDS pitch for index/row tiles
#define PW 36           // LDS pitch for W2 tile
#define NBINS 1024
#define BIN_NODES 98    // 98*1024 = 100352 >= N_NODES
#define BIN_CAP 2048    // per-bin edge capacity (mean 1562, +12 sigma)
#define EB 4096         // edges per bucket block
#define NBB 391         // bucket blocks: 391*4096 >= 1.6M

typedef __attribute__((ext_vector_type(8))) short s16x8;   // 8 bf16 (4 VGPR)
typedef __attribute__((ext_vector_type(4))) float f32x4;   // MFMA acc

// bf16 <-> fp32 helpers (RNE)
__device__ __forceinline__ float b2f(unsigned short v) {
    union { unsigned int u; float f; } x;
    x.u = ((unsigned int)v) << 16;
    return x.f;
}
__device__ __forceinline__ unsigned short f2b(float f) {
    union { float f; unsigned int u; } x;
    x.f = f;
    unsigned int r = x.u + 0x7FFFu + ((x.u >> 16) & 1u);
    return (unsigned short)(r >> 16);
}

// 8-row gather (BASE elem-ptr, STRIDE in ushorts, lane feat-offset 4*l)
// NOTE: do-while(0) so these are single statements under if() — round-9's
// brace-less `if (hb) ACC8(...)` only guarded the first of 4 statements.
#define LD8(v0, v1, v2, v3, v4, v5, v6, v7, BASE, STR, ROW, J, L)            \
    do {                                                                     \
        int s0 = (ROW)[(J)],     s1 = (ROW)[(J) + 1],                        \
            s2 = (ROW)[(J) + 2], s3 = (ROW)[(J) + 3];                        \
        int s4 = (ROW)[(J) + 4], s5 = (ROW)[(J) + 5],                        \
            s6 = (ROW)[(J) + 6], s7 = (ROW)[(J) + 7];                        \
        v0 = *(const ushort4*)((BASE) + (size_t)s0 * (STR) + 4 * (L));       \
        v1 = *(const ushort4*)((BASE) + (size_t)s1 * (STR) + 4 * (L));       \
        v2 = *(const ushort4*)((BASE) + (size_t)s2 * (STR) + 4 * (L));       \
        v3 = *(const ushort4*)((BASE) + (size_t)s3 * (STR) + 4 * (L));       \
        v4 = *(const ushort4*)((BASE) + (size_t)s4 * (STR) + 4 * (L));       \
        v5 = *(const ushort4*)((BASE) + (size_t)s5 * (STR) + 4 * (L));       \
        v6 = *(const ushort4*)((BASE) + (size_t)s6 * (STR) + 4 * (L));       \
        v7 = *(const ushort4*)((BASE) + (size_t)s7 * (STR) + 4 * (L));       \
    } while (0)

#define ACC8(A, v0, v1, v2, v3, v4, v5, v6, v7)                              \
    do {                                                                     \
        A.x += ((b2f(v0.x) + b2f(v1.x)) + (b2f(v2.x) + b2f(v3.x)))           \
             + ((b2f(v4.x) + b2f(v5.x)) + (b2f(v6.x) + b2f(v7.x)));          \
        A.y += ((b2f(v0.y) + b2f(v1.y)) + (b2f(v2.y) + b2f(v3.y)))           \
             + ((b2f(v4.y) + b2f(v5.y)) + (b2f(v6.y) + b2f(v7.y)));          \
        A.z += ((b2f(v0.z) + b2f(v1.z)) + (b2f(v2.z) + b2f(v3.z)))           \
             + ((b2f(v4.z) + b2f(v5.z)) + (b2f(v6.z) + b2f(v7.z)));          \
        A.w += ((b2f(v0.w) + b2f(v1.w)) + (b2f(v2.w) + b2f(v3.w)))           \
             + ((b2f(v4.w) + b2f(v5.w)) + (b2f(v6.w) + b2f(v7.w)));          \
    } while (0)

// ---------------- kernel A: coarse-bin edges (blocks 0..390) + MFMA GEMM1 ----
// Bucket: 4096 edges/block into 1024 bins (hist/sbase 8KB LDS).
// GEMM: u = bf16(x@W1^T) via mfma_f32_16x16x32_bf16 (round-7 proven).

__global__ __launch_bounds__(256) void k_fused0(const int* __restrict__ src,
                                                const int* __restrict__ dst,
                                                int* __restrict__ binc,        // [1024]
                                                int* __restrict__ ebuf,        // [1024*BIN_CAP]
                                                const float* __restrict__ x,
                                                const float* __restrict__ W,   // [64][128]
                                                unsigned short* __restrict__ u, // [N+1][64] bf16
                                                int n_edges, int n_nodes) {
    __shared__ __align__(16) unsigned char smraw[25600];
    int t = threadIdx.x;

    if (blockIdx.x < NBB) {
        // ---- bucket role: 4096 edges, 16/thread ----
        int* hist  = (int*)smraw;           // [1024]
        int* sbase = (int*)smraw + NBINS;   // [1024]
        for (int i = t; i < NBINS; i += 256) hist[i] = 0;
        __syncthreads();

        int estart = blockIdx.x * EB + t * 16;
        int rec[16], bn[16], rk[16];
#pragma unroll
        for (int r = 0; r < 4; ++r) {
            int e = estart + 4 * r;
            if (e + 3 < n_edges) {
                int4 d4 = *(const int4*)(dst + e);
                int4 s4 = *(const int4*)(src + e);
                int dd[4] = {d4.x, d4.y, d4.z, d4.w};
                int ss[4] = {s4.x, s4.y, s4.z, s4.w};
#pragma unroll
                for (int c = 0; c < 4; ++c) {
                    int b = dd[c] / BIN_NODES;
                    bn[4 * r + c] = b;
                    rec[4 * r + c] = ss[c] | ((dd[c] - b * BIN_NODES) << 17);
                }
            } else {
#pragma unroll
                for (int c = 0; c < 4; ++c) {
                    int ee = e + c;
                    bool ok = ee < n_edges;
                    int dd = ok ? dst[ee] : 0;
                    int ss = ok ? src[ee] : 0;
                    int b = dd / BIN_NODES;
                    bn[4 * r + c] = ok ? b : -1;
                    rec[4 * r + c] = ss | ((dd - b * BIN_NODES) << 17);
                }
            }
        }
#pragma unroll
        for (int r = 0; r < 16; ++r)
            rk[r] = (bn[r] >= 0) ? atomicAdd(&hist[bn[r]], 1) : 0;
        __syncthreads();
        for (int i = t; i < NBINS; i += 256)
            sbase[i] = (hist[i] > 0) ? atomicAdd(&binc[i], hist[i]) : 0;
        __syncthreads();
#pragma unroll
        for (int r = 0; r < 16; ++r) {
            if (bn[r] >= 0) {
                int pos = sbase[bn[r]] + rk[r];
                if (pos < BIN_CAP)
                    ebuf[(size_t)bn[r] * BIN_CAP + pos] = rec[r];
            }
        }
        return;
    }

    // ---- gemm role (round-7 proven MFMA path) ----
    int bid = blockIdx.x - NBB;
    unsigned short* wlds = (unsigned short*)smraw;            // [64][128] swizzled, 16KB
    unsigned short* sb   = (unsigned short*)(smraw + 16384);  // 4 waves x [16][72]

    int w = t >> 6, l = t & 63;
    int g = l >> 4, li = l & 15;
    int nb = bid * 64 + w * 16;

    // issue A loads early (independent of LDS)
    int xrow = nb + li;
    if (xrow > n_nodes - 1) xrow = n_nodes - 1;
    const float* xr = x + (size_t)xrow * IN_FEAT + 8 * g;
    float4 alo[4], ahi[4];
#pragma unroll
    for (int ks = 0; ks < 4; ++ks) {
        alo[ks] = *(const float4*)(xr + 32 * ks);
        ahi[ks] = *(const float4*)(xr + 32 * ks + 4);
    }

    // stage W as bf16, 16B-block swizzle: block kb of row f stored at kb^(f&7)
    {
        int f = t >> 2, k0 = (t & 3) * 32;
        const float4* wr = (const float4*)(W + (size_t)f * IN_FEAT + k0);
        unsigned short* rowp = wlds + f * 128;
#pragma unroll
        for (int i = 0; i < 8; ++i) {
            float4 v = wr[i];
            int kabs = k0 + 4 * i;
            int kb = kabs >> 3;
            int inb = kabs & 7;
            unsigned int* dp = (unsigned int*)(rowp + ((kb ^ (f & 7)) << 3) + inb);
            dp[0] = (unsigned)f2b(v.x) | ((unsigned)f2b(v.y) << 16);
            dp[1] = (unsigned)f2b(v.z) | ((unsigned)f2b(v.w) << 16);
        }
    }
    __syncthreads();

    // convert A-frags (same (g,j)->k placement as B-frags)
    s16x8 af[4];
#pragma unroll
    for (int ks = 0; ks < 4; ++ks) {
        s16x8 a;
        a[0] = (short)f2b(alo[ks].x); a[1] = (short)f2b(alo[ks].y);
        a[2] = (short)f2b(alo[ks].z); a[3] = (short)f2b(alo[ks].w);
        a[4] = (short)f2b(ahi[ks].x); a[5] = (short)f2b(ahi[ks].y);
        a[6] = (short)f2b(ahi[ks].z); a[7] = (short)f2b(ahi[ks].w);
        af[ks] = a;
    }

    f32x4 acc[4];
#pragma unroll
    for (int ft = 0; ft < 4; ++ft) acc[ft] = (f32x4){0.f, 0.f, 0.f, 0.f};

#pragma unroll
    for (int ft = 0; ft < 4; ++ft) {
        const unsigned short* wrow = wlds + (size_t)(16 * ft + li) * 128;
        int sw = li & 7;
#pragma unroll
        for (int ks = 0; ks < 4; ++ks) {
            int kb = 4 * ks + g;
            s16x8 bfr = *(const s16x8*)(wrow + ((kb ^ sw) << 3));
            acc[ft] = __builtin_amdgcn_mfma_f32_16x16x32_bf16(af[ks], bfr, acc[ft], 0, 0, 0);
        }
    }

    // epilogue: wave-private bounce (node = 4g+r rel., feat = 16ft+li)
    unsigned short* sbw = sb + w * (16 * 72);
#pragma unroll
    for (int ft = 0; ft < 4; ++ft)
#pragma unroll
        for (int r = 0; r < 4; ++r)
            sbw[(4 * g + r) * 72 + 16 * ft + li] = f2b(acc[ft][r]);

    int m2 = l >> 2, c2 = l & 3;
    uint4 p0 = *(const uint4*)(sbw + m2 * 72 + 16 * c2);
    uint4 p1 = *(const uint4*)(sbw + m2 * 72 + 16 * c2 + 8);
    int node = nb + m2;
    if (node < n_nodes) {
        uint4* up = (uint4*)(u + (size_t)node * HIDDEN + 16 * c2);
        up[0] = p0;
        up[1] = p1;
    }
}

// ---------------- kernel B: per-bin fine bucket + deg + u-normalization ----------------

__global__ __launch_bounds__(256) void k_binB(const int* __restrict__ binc,
                                              const int* __restrict__ ebuf,
                                              int* __restrict__ csr,
                                              int* __restrict__ deg,
                                              unsigned short* __restrict__ u,
                                              unsigned short* __restrict__ h2,
                                              int n_nodes) {
    __shared__ int lcur[BIN_NODES];
    int t = threadIdx.x;
    int b = blockIdx.x;

    if (t < BIN_NODES) lcur[t] = 0;
    __syncthreads();

    int cnt = binc[b];
    if (cnt > BIN_CAP) cnt = BIN_CAP;
    const int* eb = ebuf + (size_t)b * BIN_CAP;
    int nbase = b * BIN_NODES;

    for (int i = t; i < cnt; i += 256) {
        int v = eb[i];
        int sv = v & 0x1FFFF;
        int dl = v >> 17;
        int p = atomicAdd(&lcur[dl], 1);
        if (p < CAP) csr[(size_t)(nbase + dl) * CAP + p] = sv;
    }
    __syncthreads();

    // deg + sentinel-pad csr rows to multiple of 8
    if (t < BIN_NODES) {
        int node = nbase + t;
        if (node < n_nodes) {
            int dg = lcur[t];
            deg[node] = dg;
            int dgc = dg > CAP ? CAP : dg;
            int dgp = (dgc + 7) & ~7;
            for (int p = dgc; p < dgp; ++p)
                csr[(size_t)node * CAP + p] = n_nodes;   // sentinel -> zero row
        }
    }
    // normalize u rows (bf16): row = 64 ushorts = 16 ushort4 chunks
    for (int i = t; i < BIN_NODES * 16; i += 256) {
        int nl = i >> 4;
        int node = nbase + nl;
        if (node < n_nodes) {
            float dv = rsqrtf((float)(lcur[nl] + 1));
            ushort4* p = (ushort4*)(u + (size_t)node * HIDDEN) + (i & 15);
            ushort4 v = *p;
            v.x = f2b(b2f(v.x) * dv);
            v.y = f2b(b2f(v.y) * dv);
            v.z = f2b(b2f(v.z) * dv);
            v.w = f2b(b2f(v.w) * dv);
            *p = v;
        }
    }
    // zero sentinel rows
    if (b == 0) {
        ushort4 z; z.x = z.y = z.z = z.w = 0;
        if (t < 16) ((ushort4*)(u + (size_t)n_nodes * HIDDEN))[t] = z;
        if (t < 8)  ((ushort4*)(h2 + (size_t)n_nodes * OUT_FEAT))[t] = z;
    }
}

// ---------------- fused: L1 aggregation + bias + relu + GEMM2 ----------------
// Software-pipelined gather (two 8-row groups in flight); self/deg loads
// hoisted above the staging barrier; GEMM2 a-reads vectorized.

__global__ __launch_bounds__(256) void k_aggg(const unsigned short* __restrict__ u,
                                              const int* __restrict__ degA,
                                              const int* __restrict__ csr,
                                              const float* __restrict__ b1,
                                              const float* __restrict__ W2,   // [32][64]
                                              unsigned short* __restrict__ h2, // [N+1][32] bf16
                                              int n_nodes) {
    __shared__ int   sidx[16 * PS];
    __shared__ float sa[16 * PS];
    __shared__ float sdv[16];
    __shared__ float wt2[HIDDEN * PW];

    int t = threadIdx.x;
    int node0 = blockIdx.x * 16;
    int g = t >> 4;        // node-local 0..15
    int l = t & 15;        // feats 4l..4l+3
    int node = node0 + g;

    // early loads: fly under staging
    int dg = degA[node];
    ushort4 sv4 = *(const ushort4*)(u + (size_t)node * HIDDEN + 4 * l);  // self
    int dgc = dg > CAP ? CAP : dg;
    int dgp = (dgc + 7) & ~7;   // csr padded with sentinel (zero row)

    // stage: deg-aware csr (pos == l), W2 tile
    if (4 * l < dgp) {
        int4 c = *(const int4*)(csr + (size_t)node * CAP + 4 * l);
        *(int4*)(sidx + g * PS + 4 * l) = c;
    }
    for (int idx = t; idx < OUT_FEAT * HIDDEN; idx += 256) {
        int f = idx >> 6, k = idx & 63;
        wt2[k * PW + f] = W2[idx];
    }
    float dv = rsqrtf((float)(dg + 1));
    if (l == 0) sdv[g] = dv;
    __syncthreads();

    float4 acc = make_float4(b2f(sv4.x), b2f(sv4.y), b2f(sv4.z), b2f(sv4.w));
    const int* row = sidx + g * PS;
    {
        ushort4 a0, a1, a2, a3, a4, a5, a6, a7;
        ushort4 e0, e1, e2, e3, e4, e5, e6, e7;
        if (dgp > 0) {
            LD8(a0, a1, a2, a3, a4, a5, a6, a7, u, HIDDEN, row, 0, l);
            for (int j = 0; j < dgp; j += 16) {
                bool hb = (j + 8) < dgp;
                if (hb) LD8(e0, e1, e2, e3, e4, e5, e6, e7, u, HIDDEN, row, j + 8, l);
                ACC8(acc, a0, a1, a2, a3, a4, a5, a6, a7);
                if (j + 16 < dgp)
                    LD8(a0, a1, a2, a3, a4, a5, a6, a7, u, HIDDEN, row, j + 16, l);
                if (hb) ACC8(acc, e0, e1, e2, e3, e4, e5, e6, e7);
            }
        }
    }

    float4 b1v = *(const float4*)(b1 + 4 * l);
    float4 a;
    a.x = fmaxf(acc.x * dv + b1v.x, 0.f);
    a.y = fmaxf(acc.y * dv + b1v.y, 0.f);
    a.z = fmaxf(acc.z * dv + b1v.z, 0.f);
    a.w = fmaxf(acc.w * dv + b1v.w, 0.f);
    *(float4*)(sa + g * PS + 4 * l) = a;
    __syncthreads();

    // GEMM2: nl = t>>4 (16 nodes), fi = (t>>1)&7 (4 feats), dup = t&1 (k halves)
    int nl = t >> 4;
    int fi = (t >> 1) & 7;
    int dup = t & 1;
    const float* ap = sa + nl * PS + dup * 32;
    const float* wp = wt2 + (dup * 32) * PW + 4 * fi;
    float4 p = make_float4(0.f, 0.f, 0.f, 0.f);
#pragma unroll
    for (int k4 = 0; k4 < 8; ++k4) {
        float4 av = *(const float4*)(ap + 4 * k4);
        const float* wk = wp + (4 * k4) * PW;
        float4 wv0 = *(const float4*)(wk);
        float4 wv1 = *(const float4*)(wk + PW);
        float4 wv2 = *(const float4*)(wk + 2 * PW);
        float4 wv3 = *(const float4*)(wk + 3 * PW);
        p.x += av.x * wv0.x + av.y * wv1.x + av.z * wv2.x + av.w * wv3.x;
        p.y += av.x * wv0.y + av.y * wv1.y + av.z * wv2.y + av.w * wv3.y;
        p.z += av.x * wv0.z + av.y * wv1.z + av.z * wv2.z + av.w * wv3.z;
        p.w += av.x * wv0.w + av.y * wv1.w + av.z * wv2.w + av.w * wv3.w;
    }
    p.x += __shfl_xor(p.x, 1);
    p.y += __shfl_xor(p.y, 1);
    p.z += __shfl_xor(p.z, 1);
    p.w += __shfl_xor(p.w, 1);
    if (dup == 0) {
        float dvn = sdv[nl];
        ushort4 o;
        o.x = f2b(p.x * dvn); o.y = f2b(p.y * dvn);
        o.z = f2b(p.z * dvn); o.w = f2b(p.w * dvn);
        *(ushort4*)(h2 + (size_t)(node0 + nl) * OUT_FEAT + 4 * fi) = o;
    }
}

// ---------------- L2 aggregation: 32 nodes/block, software-pipelined gather ----------------

__global__ __launch_bounds__(256) void k_agg32(const unsigned short* __restrict__ h2,
                                               const int* __restrict__ degA,
                                               const int* __restrict__ csr,
                                               const float* __restrict__ b2,
                                               float* __restrict__ out, int n_nodes) {
    __shared__ int sidx[32 * PS];
    int t = threadIdx.x;
    int node0 = blockIdx.x * 32;
    int g = t >> 3;        // node-local 0..31
    int l = t & 7;         // feats 4l..4l+3
    int node = node0 + g;

    // early loads: fly under staging
    int dg = degA[node];
    ushort4 sv4 = *(const ushort4*)(h2 + (size_t)node * OUT_FEAT + 4 * l);  // self
    int dgc = dg > CAP ? CAP : dg;
    int dgp = (dgc + 7) & ~7;

#pragma unroll
    for (int r = 0; r < 2; ++r) {
        int i = t + 256 * r;
        int nl = i >> 4, pos = i & 15;
        int nd = node0 + nl;
        int dgs = degA[nd];
        if (dgs > CAP) dgs = CAP;
        dgs = (dgs + 7) & ~7;
        if (4 * pos < dgs) {
            int4 c = *(const int4*)(csr + (size_t)nd * CAP + 4 * pos);
            *(int4*)(sidx + nl * PS + 4 * pos) = c;
        }
    }
    __syncthreads();

    float dv = rsqrtf((float)(dg + 1));
    float4 acc = make_float4(b2f(sv4.x), b2f(sv4.y), b2f(sv4.z), b2f(sv4.w));
    const int* row = sidx + g * PS;
    {
        ushort4 a0, a1, a2, a3, a4, a5, a6, a7;
        ushort4 e0, e1, e2, e3, e4, e5, e6, e7;
        if (dgp > 0) {
            LD8(a0, a1, a2, a3, a4, a5, a6, a7, h2, OUT_FEAT, row, 0, l);
            for (int j = 0; j < dgp; j += 16) {
                bool hb = (j + 8) < dgp;
                if (hb) LD8(e0, e1, e2, e3, e4, e5, e6, e7, h2, OUT_FEAT, row, j + 8, l);
                ACC8(acc, a0, a1, a2, a3, a4, a5, a6, a7);
                if (j + 16 < dgp)
                    LD8(a0, a1, a2, a3, a4, a5, a6, a7, h2, OUT_FEAT, row, j + 16, l);
                if (hb) ACC8(acc, e0, e1, e2, e3, e4, e5, e6, e7);
            }
        }
    }
    float4 bv = *(const float4*)(b2 + 4 * l);
    float4 o = make_float4(acc.x * dv + bv.x, acc.y * dv + bv.y,
                           acc.z * dv + bv.z, acc.w * dv + bv.w);
    *(float4*)(out + (size_t)node * OUT_FEAT + 4 * l) = o;
}

extern "C" void kernel_launch(void* const* d_in, const int* in_sizes, int n_in,
                              void* d_out, int out_size, void* d_ws, size_t ws_size,
                              hipStream_t stream) {
    const float* x  = (const float*)d_in[0];
    const int* ei   = (const int*)d_in[1];   // [2][E]: src then dst
    const float* W1 = (const float*)d_in[2];
    const float* b1 = (const float*)d_in[3];
    const float* W2 = (const float*)d_in[4];
    const float* b2 = (const float*)d_in[5];
    float* out = (float*)d_out;

    const int* src = ei;
    const int* dst = ei + N_EDGES;

    // workspace: deg[NP] | binc[1024] | csr[N*CAP] | ebuf[1024*BIN_CAP] | u bf16 | h2 bf16
    int* deg  = (int*)d_ws;
    int* binc = deg + NP;
    int* csr  = binc + NBINS;
    int* ebuf = csr + (size_t)N_NODES * CAP;
    unsigned short* u  = (unsigned short*)(ebuf + (size_t)NBINS * BIN_CAP);
    unsigned short* h2 = u + (size_t)(N_NODES + 1) * HIDDEN;

    hipMemsetAsync(binc, 0, NBINS * sizeof(int), stream);

    // A: coarse-bin edges (first 391 blocks) + MFMA gemm1 (rest), overlapped
    k_fused0<<<NBB + 1563, 256, 0, stream>>>(src, dst, binc, ebuf, x, W1, u,
                                             N_EDGES, N_NODES);

    // B: per-bin fine bucket -> csr + deg; sentinel-pad; normalize u (bf16)
    k_binB<<<NBINS, 256, 0, stream>>>(binc, ebuf, csr, deg, u, h2, N_NODES);

    // L1 aggregation + bias + relu + GEMM2 -> h2' (bf16)
    k_aggg<<<N_NODES / 16, 256, 0, stream>>>(u, deg, csr, b1, W2, h2, N_NODES);

    // L2 aggregation + bias -> out (fp32)
    k_agg32<<<N_NODES / 32, 256, 0, stream>>>(h2, deg, csr, b2, out, N_NODES);
}

// Round 11
// 203.025 us; speedup vs baseline: 1.0218x; 1.0218x over previous
//
#include <hip/hip_runtime.h>
#include <hip/hip_bf16.h>

#define N_NODES 100000
#define N_EDGES 1600000
#define IN_FEAT 128
#define HIDDEN 64
#define OUT_FEAT 32
#define CAP 64          // padded CSR slots/node
#define NP 100352       // padded node count
#define PS 68           // LDS pitch for index/row tiles
#define PW 36           // LDS pitch for W2 tile
#define NBINS 1024
#define BIN_NODES 98    // 98*1024 = 100352 >= N_NODES
#define BIN_CAP 2048    // per-bin edge capacity (mean 1562, +12 sigma)
#define EB 4096         // edges per bucket block
#define NBB 391         // bucket blocks: 391*4096 >= 1.6M

typedef __attribute__((ext_vector_type(8))) short s16x8;   // 8 bf16 (4 VGPR)
typedef __attribute__((ext_vector_type(4))) float f32x4;   // MFMA acc

// bf16 <-> fp32 helpers (RNE)
__device__ __forceinline__ float b2f(unsigned short v) {
    union { unsigned int u; float f; } x;
    x.u = ((unsigned int)v) << 16;
    return x.f;
}
__device__ __forceinline__ unsigned short f2b(float f) {
    union { float f; unsigned int u; } x;
    x.f = f;
    unsigned int r = x.u + 0x7FFFu + ((x.u >> 16) & 1u);
    return (unsigned short)(r >> 16);
}

// ---------------- kernel A: coarse-bin edges (blocks 0..390) + MFMA GEMM1 ----
// Bucket: 4096 edges/block into 1024 bins (hist/sbase 8KB LDS).
// GEMM: u = bf16(x@W1^T) via mfma_f32_16x16x32_bf16 (round-7 proven).

__global__ __launch_bounds__(256) void k_fused0(const int* __restrict__ src,
                                                const int* __restrict__ dst,
                                                int* __restrict__ binc,        // [1024]
                                                int* __restrict__ ebuf,        // [1024*BIN_CAP]
                                                const float* __restrict__ x,
                                                const float* __restrict__ W,   // [64][128]
                                                unsigned short* __restrict__ u, // [N+1][64] bf16
                                                int n_edges, int n_nodes) {
    __shared__ __align__(16) unsigned char smraw[25600];
    int t = threadIdx.x;

    if (blockIdx.x < NBB) {
        // ---- bucket role: 4096 edges, 16/thread ----
        int* hist  = (int*)smraw;           // [1024]
        int* sbase = (int*)smraw + NBINS;   // [1024]
        for (int i = t; i < NBINS; i += 256) hist[i] = 0;
        __syncthreads();

        int estart = blockIdx.x * EB + t * 16;
        int rec[16], bn[16], rk[16];
#pragma unroll
        for (int r = 0; r < 4; ++r) {
            int e = estart + 4 * r;
            if (e + 3 < n_edges) {
                int4 d4 = *(const int4*)(dst + e);
                int4 s4 = *(const int4*)(src + e);
                int dd[4] = {d4.x, d4.y, d4.z, d4.w};
                int ss[4] = {s4.x, s4.y, s4.z, s4.w};
#pragma unroll
                for (int c = 0; c < 4; ++c) {
                    int b = dd[c] / BIN_NODES;
                    bn[4 * r + c] = b;
                    rec[4 * r + c] = ss[c] | ((dd[c] - b * BIN_NODES) << 17);
                }
            } else {
#pragma unroll
                for (int c = 0; c < 4; ++c) {
                    int ee = e + c;
                    bool ok = ee < n_edges;
                    int dd = ok ? dst[ee] : 0;
                    int ss = ok ? src[ee] : 0;
                    int b = dd / BIN_NODES;
                    bn[4 * r + c] = ok ? b : -1;
                    rec[4 * r + c] = ss | ((dd - b * BIN_NODES) << 17);
                }
            }
        }
#pragma unroll
        for (int r = 0; r < 16; ++r)
            rk[r] = (bn[r] >= 0) ? atomicAdd(&hist[bn[r]], 1) : 0;
        __syncthreads();
        for (int i = t; i < NBINS; i += 256)
            sbase[i] = (hist[i] > 0) ? atomicAdd(&binc[i], hist[i]) : 0;
        __syncthreads();
#pragma unroll
        for (int r = 0; r < 16; ++r) {
            if (bn[r] >= 0) {
                int pos = sbase[bn[r]] + rk[r];
                if (pos < BIN_CAP)
                    ebuf[(size_t)bn[r] * BIN_CAP + pos] = rec[r];
            }
        }
        return;
    }

    // ---- gemm role (round-7 proven MFMA path) ----
    int bid = blockIdx.x - NBB;
    unsigned short* wlds = (unsigned short*)smraw;            // [64][128] swizzled, 16KB
    unsigned short* sb   = (unsigned short*)(smraw + 16384);  // 4 waves x [16][72]

    int w = t >> 6, l = t & 63;
    int g = l >> 4, li = l & 15;
    int nb = bid * 64 + w * 16;

    // issue A loads early (independent of LDS)
    int xrow = nb + li;
    if (xrow > n_nodes - 1) xrow = n_nodes - 1;
    const float* xr = x + (size_t)xrow * IN_FEAT + 8 * g;
    float4 alo[4], ahi[4];
#pragma unroll
    for (int ks = 0; ks < 4; ++ks) {
        alo[ks] = *(const float4*)(xr + 32 * ks);
        ahi[ks] = *(const float4*)(xr + 32 * ks + 4);
    }

    // stage W as bf16, 16B-block swizzle: block kb of row f stored at kb^(f&7)
    {
        int f = t >> 2, k0 = (t & 3) * 32;
        const float4* wr = (const float4*)(W + (size_t)f * IN_FEAT + k0);
        unsigned short* rowp = wlds + f * 128;
#pragma unroll
        for (int i = 0; i < 8; ++i) {
            float4 v = wr[i];
            int kabs = k0 + 4 * i;
            int kb = kabs >> 3;
            int inb = kabs & 7;
            unsigned int* dp = (unsigned int*)(rowp + ((kb ^ (f & 7)) << 3) + inb);
            dp[0] = (unsigned)f2b(v.x) | ((unsigned)f2b(v.y) << 16);
            dp[1] = (unsigned)f2b(v.z) | ((unsigned)f2b(v.w) << 16);
        }
    }
    __syncthreads();

    // convert A-frags (same (g,j)->k placement as B-frags)
    s16x8 af[4];
#pragma unroll
    for (int ks = 0; ks < 4; ++ks) {
        s16x8 a;
        a[0] = (short)f2b(alo[ks].x); a[1] = (short)f2b(alo[ks].y);
        a[2] = (short)f2b(alo[ks].z); a[3] = (short)f2b(alo[ks].w);
        a[4] = (short)f2b(ahi[ks].x); a[5] = (short)f2b(ahi[ks].y);
        a[6] = (short)f2b(ahi[ks].z); a[7] = (short)f2b(ahi[ks].w);
        af[ks] = a;
    }

    f32x4 acc[4];
#pragma unroll
    for (int ft = 0; ft < 4; ++ft) acc[ft] = (f32x4){0.f, 0.f, 0.f, 0.f};

#pragma unroll
    for (int ft = 0; ft < 4; ++ft) {
        const unsigned short* wrow = wlds + (size_t)(16 * ft + li) * 128;
        int sw = li & 7;
#pragma unroll
        for (int ks = 0; ks < 4; ++ks) {
            int kb = 4 * ks + g;
            s16x8 bfr = *(const s16x8*)(wrow + ((kb ^ sw) << 3));
            acc[ft] = __builtin_amdgcn_mfma_f32_16x16x32_bf16(af[ks], bfr, acc[ft], 0, 0, 0);
        }
    }

    // epilogue: wave-private bounce (node = 4g+r rel., feat = 16ft+li)
    unsigned short* sbw = sb + w * (16 * 72);
#pragma unroll
    for (int ft = 0; ft < 4; ++ft)
#pragma unroll
        for (int r = 0; r < 4; ++r)
            sbw[(4 * g + r) * 72 + 16 * ft + li] = f2b(acc[ft][r]);

    int m2 = l >> 2, c2 = l & 3;
    uint4 p0 = *(const uint4*)(sbw + m2 * 72 + 16 * c2);
    uint4 p1 = *(const uint4*)(sbw + m2 * 72 + 16 * c2 + 8);
    int node = nb + m2;
    if (node < n_nodes) {
        uint4* up = (uint4*)(u + (size_t)node * HIDDEN + 16 * c2);
        up[0] = p0;
        up[1] = p1;
    }
}

// ---------------- kernel B: per-bin fine bucket + deg + dinv ----------------
// 1024 blocks (4/CU). u is NOT normalized here: dinv[node] written instead
// (aggg scales per-source). Saves the 25.6MB u read-modify-write pass.
// Sentinel rows of u/h2 zeroed; dinv[n_nodes] = 0 keeps padded slots inert.

__global__ __launch_bounds__(256) void k_binB(const int* __restrict__ binc,
                                              const int* __restrict__ ebuf,
                                              int* __restrict__ csr,
                                              int* __restrict__ deg,
                                              float* __restrict__ dinv,
                                              unsigned short* __restrict__ u,
                                              unsigned short* __restrict__ h2,
                                              int n_nodes) {
    __shared__ int lcur[BIN_NODES];
    int t = threadIdx.x;
    int b = blockIdx.x;

    if (t < BIN_NODES) lcur[t] = 0;
    __syncthreads();

    int cnt = binc[b];
    if (cnt > BIN_CAP) cnt = BIN_CAP;
    const int* eb = ebuf + (size_t)b * BIN_CAP;
    int nbase = b * BIN_NODES;

    for (int i = t; i < cnt; i += 256) {
        int v = eb[i];
        int sv = v & 0x1FFFF;
        int dl = v >> 17;
        int p = atomicAdd(&lcur[dl], 1);
        if (p < CAP) csr[(size_t)(nbase + dl) * CAP + p] = sv;
    }
    __syncthreads();

    // deg + dinv + sentinel-pad csr rows to multiple of 8
    if (t < BIN_NODES) {
        int node = nbase + t;
        if (node < n_nodes) {
            int dg = lcur[t];
            deg[node] = dg;
            dinv[node] = rsqrtf((float)(dg + 1));
            int dgc = dg > CAP ? CAP : dg;
            int dgp = (dgc + 7) & ~7;
            for (int p = dgc; p < dgp; ++p)
                csr[(size_t)node * CAP + p] = n_nodes;   // sentinel -> zero row
        }
    }
    // zero sentinel rows + sentinel dinv
    if (b == 0) {
        ushort4 z; z.x = z.y = z.z = z.w = 0;
        if (t < 16) ((ushort4*)(u + (size_t)n_nodes * HIDDEN))[t] = z;
        if (t < 8)  ((ushort4*)(h2 + (size_t)n_nodes * OUT_FEAT))[t] = z;
        if (t == 0) dinv[n_nodes] = 0.f;
    }
}

// ---------------- fused: L1 aggregation + bias + relu + GEMM2 ----------------
// u raw bf16; per-source scale dinv[s] (L2-resident 400KB):
// agg[d] = dv_d*(dv_d*u[d] + sum_s dinv[s]*u[s]) + b1;
// h2' = bf16(dv_d*(relu(agg) @ W2^T)). Deg-aware CSR staging.

__global__ __launch_bounds__(256) void k_aggg(const unsigned short* __restrict__ u,
                                              const int* __restrict__ degA,
                                              const float* __restrict__ dinv,
                                              const int* __restrict__ csr,
                                              const float* __restrict__ b1,
                                              const float* __restrict__ W2,   // [32][64]
                                              unsigned short* __restrict__ h2, // [N+1][32] bf16
                                              int n_nodes) {
    __shared__ int   sidx[16 * PS];
    __shared__ float sa[16 * PS];
    __shared__ float sdv[16];
    __shared__ float wt2[HIDDEN * PW];

    int t = threadIdx.x;
    int node0 = blockIdx.x * 16;

    for (int idx = t; idx < OUT_FEAT * HIDDEN; idx += 256) {
        int f = idx >> 6, k = idx & 63;
        wt2[k * PW + f] = W2[idx];
    }
    {
        int nl = t >> 4, pos = t & 15;
        int nd = node0 + nl;
        int dgs = degA[nd];
        if (dgs > CAP) dgs = CAP;
        dgs = (dgs + 7) & ~7;
        if (4 * pos < dgs) {
            int4 c = *(const int4*)(csr + (size_t)nd * CAP + 4 * pos);
            *(int4*)(sidx + nl * PS + 4 * pos) = c;
        }
    }
    __syncthreads();

    int g = t >> 4;        // node-local 0..15
    int l = t & 15;        // feats 4l..4l+3
    int node = node0 + g;
    int dg = degA[node];
    float dv = rsqrtf((float)(dg + 1));
    if (l == 0) sdv[g] = dv;
    int dgc = dg > CAP ? CAP : dg;
    int dgp = (dgc + 7) & ~7;   // csr padded with sentinel (zero row)

    ushort4 sv4 = *(const ushort4*)(u + (size_t)node * HIDDEN + 4 * l);  // self
    float4 acc = make_float4(dv * b2f(sv4.x), dv * b2f(sv4.y),
                             dv * b2f(sv4.z), dv * b2f(sv4.w));
    const int* row = sidx + g * PS;
    for (int j = 0; j < dgp; j += 8) {
        int s0 = row[j],     s1 = row[j + 1], s2 = row[j + 2], s3 = row[j + 3];
        int s4 = row[j + 4], s5 = row[j + 5], s6 = row[j + 6], s7 = row[j + 7];
        float d0 = dinv[s0], d1 = dinv[s1], d2 = dinv[s2], d3 = dinv[s3];
        float d4 = dinv[s4], d5 = dinv[s5], d6 = dinv[s6], d7 = dinv[s7];
        ushort4 r0 = *(const ushort4*)(u + (size_t)s0 * HIDDEN + 4 * l);
        ushort4 r1 = *(const ushort4*)(u + (size_t)s1 * HIDDEN + 4 * l);
        ushort4 r2 = *(const ushort4*)(u + (size_t)s2 * HIDDEN + 4 * l);
        ushort4 r3 = *(const ushort4*)(u + (size_t)s3 * HIDDEN + 4 * l);
        ushort4 r4 = *(const ushort4*)(u + (size_t)s4 * HIDDEN + 4 * l);
        ushort4 r5 = *(const ushort4*)(u + (size_t)s5 * HIDDEN + 4 * l);
        ushort4 r6 = *(const ushort4*)(u + (size_t)s6 * HIDDEN + 4 * l);
        ushort4 r7 = *(const ushort4*)(u + (size_t)s7 * HIDDEN + 4 * l);
        acc.x += ((d0 * b2f(r0.x) + d1 * b2f(r1.x)) + (d2 * b2f(r2.x) + d3 * b2f(r3.x)))
               + ((d4 * b2f(r4.x) + d5 * b2f(r5.x)) + (d6 * b2f(r6.x) + d7 * b2f(r7.x)));
        acc.y += ((d0 * b2f(r0.y) + d1 * b2f(r1.y)) + (d2 * b2f(r2.y) + d3 * b2f(r3.y)))
               + ((d4 * b2f(r4.y) + d5 * b2f(r5.y)) + (d6 * b2f(r6.y) + d7 * b2f(r7.y)));
        acc.z += ((d0 * b2f(r0.z) + d1 * b2f(r1.z)) + (d2 * b2f(r2.z) + d3 * b2f(r3.z)))
               + ((d4 * b2f(r4.z) + d5 * b2f(r5.z)) + (d6 * b2f(r6.z) + d7 * b2f(r7.z)));
        acc.w += ((d0 * b2f(r0.w) + d1 * b2f(r1.w)) + (d2 * b2f(r2.w) + d3 * b2f(r3.w)))
               + ((d4 * b2f(r4.w) + d5 * b2f(r5.w)) + (d6 * b2f(r6.w) + d7 * b2f(r7.w)));
    }

    float4 b1v = *(const float4*)(b1 + 4 * l);
    float4 a;
    a.x = fmaxf(acc.x * dv + b1v.x, 0.f);
    a.y = fmaxf(acc.y * dv + b1v.y, 0.f);
    a.z = fmaxf(acc.z * dv + b1v.z, 0.f);
    a.w = fmaxf(acc.w * dv + b1v.w, 0.f);
    *(float4*)(sa + g * PS + 4 * l) = a;
    __syncthreads();

    // GEMM2: nl = t>>4 (16 nodes), fi = (t>>1)&7 (4 feats), dup = t&1 (k halves)
    int nl = t >> 4;
    int fi = (t >> 1) & 7;
    int dup = t & 1;
    const float* ap = sa + nl * PS + dup * 32;
    const float* wp = wt2 + (dup * 32) * PW + 4 * fi;
    float4 p = make_float4(0.f, 0.f, 0.f, 0.f);
#pragma unroll
    for (int k = 0; k < 32; ++k) {
        float av = ap[k];
        float4 wv = *(const float4*)(wp + k * PW);
        p.x += av * wv.x; p.y += av * wv.y;
        p.z += av * wv.z; p.w += av * wv.w;
    }
    p.x += __shfl_xor(p.x, 1);
    p.y += __shfl_xor(p.y, 1);
    p.z += __shfl_xor(p.z, 1);
    p.w += __shfl_xor(p.w, 1);
    if (dup == 0) {
        float dvn = sdv[nl];
        ushort4 o;
        o.x = f2b(p.x * dvn); o.y = f2b(p.y * dvn);
        o.z = f2b(p.z * dvn); o.w = f2b(p.w * dvn);
        *(ushort4*)(h2 + (size_t)(node0 + nl) * OUT_FEAT + 4 * fi) = o;
    }
}

// ---------------- L2 aggregation: 32 nodes/block, 8 lanes x 4 feats per node ----------------
// out[d] = dinv_d*(h2'[d] + sum_s h2'[s]) + b2 (h2' pre-scaled by dinv_s).

__global__ __launch_bounds__(256) void k_agg32(const unsigned short* __restrict__ h2,
                                               const int* __restrict__ degA,
                                               const int* __restrict__ csr,
                                               const float* __restrict__ b2,
                                               float* __restrict__ out, int n_nodes) {
    __shared__ int sidx[32 * PS];
    int t = threadIdx.x;
    int node0 = blockIdx.x * 32;

#pragma unroll
    for (int r = 0; r < 2; ++r) {
        int i = t + 256 * r;
        int nl = i >> 4, pos = i & 15;
        int nd = node0 + nl;
        int dgs = degA[nd];
        if (dgs > CAP) dgs = CAP;
        dgs = (dgs + 7) & ~7;
        if (4 * pos < dgs) {
            int4 c = *(const int4*)(csr + (size_t)nd * CAP + 4 * pos);
            *(int4*)(sidx + nl * PS + 4 * pos) = c;
        }
    }
    __syncthreads();

    int g = t >> 3;        // node-local 0..31
    int l = t & 7;         // feats 4l..4l+3
    int node = node0 + g;
    int dg = degA[node];
    float dv = rsqrtf((float)(dg + 1));
    int dgc = dg > CAP ? CAP : dg;
    int dgp = (dgc + 7) & ~7;

    ushort4 sv4 = *(const ushort4*)(h2 + (size_t)node * OUT_FEAT + 4 * l);  // self
    float4 acc = make_float4(b2f(sv4.x), b2f(sv4.y), b2f(sv4.z), b2f(sv4.w));
    const int* row = sidx + g * PS;
    for (int j = 0; j < dgp; j += 8) {
        int s0 = row[j],     s1 = row[j + 1], s2 = row[j + 2], s3 = row[j + 3];
        int s4 = row[j + 4], s5 = row[j + 5], s6 = row[j + 6], s7 = row[j + 7];
        ushort4 r0 = *(const ushort4*)(h2 + (size_t)s0 * OUT_FEAT + 4 * l);
        ushort4 r1 = *(const ushort4*)(h2 + (size_t)s1 * OUT_FEAT + 4 * l);
        ushort4 r2 = *(const ushort4*)(h2 + (size_t)s2 * OUT_FEAT + 4 * l);
        ushort4 r3 = *(const ushort4*)(h2 + (size_t)s3 * OUT_FEAT + 4 * l);
        ushort4 r4 = *(const ushort4*)(h2 + (size_t)s4 * OUT_FEAT + 4 * l);
        ushort4 r5 = *(const ushort4*)(h2 + (size_t)s5 * OUT_FEAT + 4 * l);
        ushort4 r6 = *(const ushort4*)(h2 + (size_t)s6 * OUT_FEAT + 4 * l);
        ushort4 r7 = *(const ushort4*)(h2 + (size_t)s7 * OUT_FEAT + 4 * l);
        acc.x += ((b2f(r0.x) + b2f(r1.x)) + (b2f(r2.x) + b2f(r3.x)))
               + ((b2f(r4.x) + b2f(r5.x)) + (b2f(r6.x) + b2f(r7.x)));
        acc.y += ((b2f(r0.y) + b2f(r1.y)) + (b2f(r2.y) + b2f(r3.y)))
               + ((b2f(r4.y) + b2f(r5.y)) + (b2f(r6.y) + b2f(r7.y)));
        acc.z += ((b2f(r0.z) + b2f(r1.z)) + (b2f(r2.z) + b2f(r3.z)))
               + ((b2f(r4.z) + b2f(r5.z)) + (b2f(r6.z) + b2f(r7.z)));
        acc.w += ((b2f(r0.w) + b2f(r1.w)) + (b2f(r2.w) + b2f(r3.w)))
               + ((b2f(r4.w) + b2f(r5.w)) + (b2f(r6.w) + b2f(r7.w)));
    }
    float4 bv = *(const float4*)(b2 + 4 * l);
    float4 o = make_float4(acc.x * dv + bv.x, acc.y * dv + bv.y,
                           acc.z * dv + bv.z, acc.w * dv + bv.w);
    *(float4*)(out + (size_t)node * OUT_FEAT + 4 * l) = o;
}

extern "C" void kernel_launch(void* const* d_in, const int* in_sizes, int n_in,
                              void* d_out, int out_size, void* d_ws, size_t ws_size,
                              hipStream_t stream) {
    const float* x  = (const float*)d_in[0];
    const int* ei   = (const int*)d_in[1];   // [2][E]: src then dst
    const float* W1 = (const float*)d_in[2];
    const float* b1 = (const float*)d_in[3];
    const float* W2 = (const float*)d_in[4];
    const float* b2 = (const float*)d_in[5];
    float* out = (float*)d_out;

    const int* src = ei;
    const int* dst = ei + N_EDGES;

    // workspace: deg[NP] | dinv[NP] | binc[1024] | csr[N*CAP] | ebuf | u bf16 | h2 bf16
    int* deg    = (int*)d_ws;
    float* dinv = (float*)(deg + NP);
    int* binc   = (int*)(dinv + NP);
    int* csr    = binc + NBINS;
    int* ebuf   = csr + (size_t)N_NODES * CAP;
    unsigned short* u  = (unsigned short*)(ebuf + (size_t)NBINS * BIN_CAP);
    unsigned short* h2 = u + (size_t)(N_NODES + 1) * HIDDEN;

    hipMemsetAsync(binc, 0, NBINS * sizeof(int), stream);

    // A: coarse-bin edges (first 391 blocks) + MFMA gemm1 (rest), overlapped
    k_fused0<<<NBB + 1563, 256, 0, stream>>>(src, dst, binc, ebuf, x, W1, u,
                                             N_EDGES, N_NODES);

    // B: per-bin fine bucket -> csr + deg + dinv; sentinel-pad
    k_binB<<<NBINS, 256, 0, stream>>>(binc, ebuf, csr, deg, dinv, u, h2, N_NODES);

    // L1 aggregation (dinv-scaled) + bias + relu + GEMM2 -> h2' (bf16)
    k_aggg<<<N_NODES / 16, 256, 0, stream>>>(u, deg, dinv, csr, b1, W2, h2, N_NODES);

    // L2 aggregation + bias -> out (fp32)
    k_agg32<<<N_NODES / 32, 256, 0, stream>>>(h2, deg, csr, b2, out, N_NODES);
}